// Round 4
// baseline (520.504 us; speedup 1.0000x reference)
//
#include <hip/hip_runtime.h>

#define N_NODES 100000
#define E_EDGES 300000
#define N_GRAPHS 2048

typedef float  floatx4 __attribute__((ext_vector_type(4)));
typedef short  shortx8 __attribute__((ext_vector_type(8)));

__device__ __forceinline__ float bf2f(unsigned short u) {
  return __uint_as_float(((unsigned int)u) << 16);
}
__device__ __forceinline__ unsigned short f2bf(float f) {
  unsigned int u = __float_as_uint(f);
  u += 0x7FFFu + ((u >> 16) & 1u);
  return (unsigned short)(u >> 16);
}

// async global->LDS, 16B per lane; lds base wave-uniform, dst = base+lane*16 (m104)
__device__ __forceinline__ void cp16(const void* g, void* l) {
  __builtin_amdgcn_global_load_lds(
      (const __attribute__((address_space(1))) unsigned int*)g,
      (__attribute__((address_space(3))) unsigned int*)l, 16, 0, 0);
}

// ---- prep kernel: all independent prologue work in ONE dispatch -------------
struct PrepArgs {
  const float* W[4];
  unsigned short* Wt[4];
  int K[4];
  int N[4];
  const float* We;
  const float* be;
  const float* W1_0;
  unsigned short* WfT;
  const float* W2_2;
  const float* b2_2;
  const float* wtask;
  float* w2v;
  float* c2;
  float* nodedot;
  float* out;
  const float* b_task;
};

__global__ __launch_bounds__(256)
void prep_kernel(PrepArgs a) {
  const int blk = blockIdx.x;
  if (blk < 320) {
    int z, b;
    if (blk < 64)       { z = 0; b = blk; }
    else if (blk < 128) { z = 1; b = blk - 64; }
    else if (blk < 192) { z = 2; b = blk - 128; }
    else                { z = 3; b = blk - 192; }
    const int K = a.K[z], N = a.N[z];
    const int nt = N / 32;
    const int kb = (b / nt) * 32, nb = (b % nt) * 32;
    __shared__ unsigned short tile[32][33];
    const float* W = a.W[z];
    unsigned short* Wt = a.Wt[z];
    const int tx = threadIdx.x & 31, ty = threadIdx.x >> 5;
    for (int r = ty; r < 32; r += 8)
      tile[r][tx] = f2bf(W[(size_t)(kb + r) * N + nb + tx]);
    __syncthreads();
    for (int r = ty; r < 32; r += 8)
      Wt[(size_t)(nb + r) * K + kb + tx] = tile[tx][r];
  } else if (blk < 361) {
    const int k = blk - 320;  // 0..40
    const int n = threadIdx.x;
    if (k < 40) {
      float s = 0.f;
      for (int j = 0; j < 128; j++) s = fmaf(a.We[k * 128 + j], a.W1_0[(size_t)j * 256 + n], s);
      a.WfT[n * 64 + k] = f2bf(s);
    } else {
      float s = 0.f;
      for (int j = 0; j < 128; j++) s = fmaf(a.be[j], a.W1_0[(size_t)j * 256 + n], s);
      a.WfT[n * 64 + 40] = f2bf(s);
      for (int kk = 41; kk < 64; kk++) a.WfT[n * 64 + kk] = 0;
    }
  } else if (blk < 490) {
    const int p = blk - 361;  // 0..128
    const int lane = threadIdx.x & 63;
    const int wave = threadIdx.x >> 6;
    if (p < 128) {
      const int k = p * 4 + wave;
      const float* row = a.W2_2 + (size_t)k * 512 + lane * 8;
      float4 a0 = *(const float4*)(row);
      float4 a1 = *(const float4*)(row + 4);
      float4 w0 = *(const float4*)(a.wtask + lane * 8);
      float4 w1 = *(const float4*)(a.wtask + lane * 8 + 4);
      float s = a0.x * w0.x + a0.y * w0.y + a0.z * w0.z + a0.w * w0.w +
                a1.x * w1.x + a1.y * w1.y + a1.z * w1.z + a1.w * w1.w;
#pragma unroll
      for (int off = 32; off > 0; off >>= 1) s += __shfl_down(s, off);
      if (lane == 0) a.w2v[k] = s;
    } else if (wave == 0) {
      float4 a0 = *(const float4*)(a.b2_2 + lane * 8);
      float4 a1 = *(const float4*)(a.b2_2 + lane * 8 + 4);
      float4 w0 = *(const float4*)(a.wtask + lane * 8);
      float4 w1 = *(const float4*)(a.wtask + lane * 8 + 4);
      float s = a0.x * w0.x + a0.y * w0.y + a0.z * w0.z + a0.w * w0.w +
                a1.x * w1.x + a1.y * w1.y + a1.z * w1.z + a1.w * w1.w;
#pragma unroll
      for (int off = 32; off > 0; off >>= 1) s += __shfl_down(s, off);
      if (lane == 0) *a.c2 = s;
    }
  } else if (blk < 881) {
    int i = (blk - 490) * 256 + threadIdx.x;
    if (i < N_NODES) a.nodedot[i] = 0.f;
  } else {
    int g = (blk - 881) * 256 + threadIdx.x;
    if (g < N_GRAPHS) a.out[g] = a.b_task[0];
  }
}

// ---------------- CSR build: zero, histogram, scan, fill ---------------------
__global__ __launch_bounds__(256)
void zero_kernel(int* __restrict__ p, int n) {
  int i = blockIdx.x * 256 + threadIdx.x;
  if (i < n) p[i] = 0;
}

__global__ __launch_bounds__(256)
void hist_kernel(const int* __restrict__ ei, int* __restrict__ deg) {
  int e = blockIdx.x * 256 + threadIdx.x;
  if (e < E_EDGES) atomicAdd(&deg[ei[E_EDGES + e]], 1);
}

__global__ __launch_bounds__(256)
void scan_blk_kernel(const int* __restrict__ in, int* __restrict__ out,
                     int* __restrict__ blk_sums, int n_in, int n_out) {
  __shared__ int sm[256];
  const int t = threadIdx.x;
  const int base = blockIdx.x * 1024 + t * 4;
  int d0 = (base + 0 < n_in) ? in[base + 0] : 0;
  int d1 = (base + 1 < n_in) ? in[base + 1] : 0;
  int d2 = (base + 2 < n_in) ? in[base + 2] : 0;
  int d3 = (base + 3 < n_in) ? in[base + 3] : 0;
  int s = d0 + d1 + d2 + d3;
  sm[t] = s;
  __syncthreads();
  for (int off = 1; off < 256; off <<= 1) {
    int v = (t >= off) ? sm[t - off] : 0;
    __syncthreads();
    sm[t] += v;
    __syncthreads();
  }
  int excl = sm[t] - s;
  if (base + 0 < n_out) out[base + 0] = excl;
  if (base + 1 < n_out) out[base + 1] = excl + d0;
  if (base + 2 < n_out) out[base + 2] = excl + d0 + d1;
  if (base + 3 < n_out) out[base + 3] = excl + d0 + d1 + d2;
  if (t == 255 && blk_sums) blk_sums[blockIdx.x] = sm[255];
}

__global__ __launch_bounds__(256)
void scan_fix_kernel(int* __restrict__ row_ptr, const int* __restrict__ blk_off,
                     int* __restrict__ cursor) {
  int i = blockIdx.x * 256 + threadIdx.x;
  if (i <= N_NODES) {
    int v = row_ptr[i] + blk_off[i >> 10];
    row_ptr[i] = v;
    if (i < N_NODES) cursor[i] = v;
  }
}

__global__ __launch_bounds__(256)
void fill_kernel(const int* __restrict__ ei, int* __restrict__ cursor,
                 int* __restrict__ csr_src) {
  int e = blockIdx.x * 256 + threadIdx.x;
  if (e < E_EDGES) {
    int d = ei[E_EDGES + e];
    int slot = atomicAdd(&cursor[d], 1);
    csr_src[slot] = ei[e];
  }
}

// ---- gatherx: G[n,64] = bf16([(1+eps)X_n + sum X_src | f_n | 0...]) ---------
__global__ __launch_bounds__(256)
void gatherx_kernel(const float* __restrict__ X, unsigned short* __restrict__ G,
                    const int* __restrict__ row_ptr, const int* __restrict__ csr,
                    const float* __restrict__ eps) {
  const int node = blockIdx.x * 4 + (threadIdx.x >> 6);
  const int lane = threadIdx.x & 63;
  const float sc = 1.0f + eps[0];
  const int e0 = row_ptr[node];
  const int e1 = row_ptr[node + 1];
  float acc = 0.f;
  if (lane < 40) {
    acc = sc * X[(size_t)node * 40 + lane];
    int e = e0;
    for (; e + 4 <= e1; e += 4) {
      int s0 = csr[e], s1 = csr[e + 1], s2 = csr[e + 2], s3 = csr[e + 3];
      float a0 = X[(size_t)s0 * 40 + lane];
      float a1 = X[(size_t)s1 * 40 + lane];
      float a2 = X[(size_t)s2 * 40 + lane];
      float a3 = X[(size_t)s3 * 40 + lane];
      acc += (a0 + a1) + (a2 + a3);
    }
    for (; e < e1; e++)
      acc += X[(size_t)csr[e] * 40 + lane];
  } else if (lane == 40) {
    acc = sc + (float)(e1 - e0);
  }
  G[(size_t)node * 64 + lane] = f2bf(acc);
}

// ------- gather (D=256): Z[d] = bf16((1+eps)*H[d] + sum H[src]) --------------
// R14 exact form: ONE wave per node, uint2 (8B) loads, simple loop.
__global__ __launch_bounds__(256)
void gather_kernel(const unsigned short* __restrict__ H, unsigned short* __restrict__ Z,
                   const int* __restrict__ row_ptr, const int* __restrict__ csr,
                   const float* __restrict__ eps, int l) {
  const int node = blockIdx.x * 4 + (threadIdx.x >> 6);
  const int lane = threadIdx.x & 63;
  const float sc = 1.0f + eps[l];
  uint2 hv = *(const uint2*)(H + (size_t)node * 256 + lane * 4);
  float acc[4];
  acc[0] = sc * bf2f((unsigned short)(hv.x & 0xFFFF));
  acc[1] = sc * bf2f((unsigned short)(hv.x >> 16));
  acc[2] = sc * bf2f((unsigned short)(hv.y & 0xFFFF));
  acc[3] = sc * bf2f((unsigned short)(hv.y >> 16));
  const int e0 = row_ptr[node];
  const int e1 = row_ptr[node + 1];
  int e = e0;
  for (; e + 2 <= e1; e += 2) {
    int s0 = csr[e], s1 = csr[e + 1];
    uint2 a = *(const uint2*)(H + (size_t)s0 * 256 + lane * 4);
    uint2 b = *(const uint2*)(H + (size_t)s1 * 256 + lane * 4);
    acc[0] += bf2f((unsigned short)(a.x & 0xFFFF)) + bf2f((unsigned short)(b.x & 0xFFFF));
    acc[1] += bf2f((unsigned short)(a.x >> 16))    + bf2f((unsigned short)(b.x >> 16));
    acc[2] += bf2f((unsigned short)(a.y & 0xFFFF)) + bf2f((unsigned short)(b.y & 0xFFFF));
    acc[3] += bf2f((unsigned short)(a.y >> 16))    + bf2f((unsigned short)(b.y >> 16));
  }
  if (e < e1) {
    int s0 = csr[e];
    uint2 a = *(const uint2*)(H + (size_t)s0 * 256 + lane * 4);
    acc[0] += bf2f((unsigned short)(a.x & 0xFFFF));
    acc[1] += bf2f((unsigned short)(a.x >> 16));
    acc[2] += bf2f((unsigned short)(a.y & 0xFFFF));
    acc[3] += bf2f((unsigned short)(a.y >> 16));
  }
  unsigned short z[4] = {f2bf(acc[0]), f2bf(acc[1]), f2bf(acc[2]), f2bf(acc[3])};
  *(uint2*)(Z + (size_t)node * 256 + lane * 4) = *(uint2*)z;
}

// ============================================================================
// R20 (resubmit; R3 bench was a container-infra failure, not a kernel result):
// fused per-layer MLP, BARRIER-FREE K-loops.
// R19 post-mortem: 69.9us/dispatch, MfmaUtil 14% -- the per-K-step
// {cp16(W) -> syncthreads(vmcnt(0) drain) -> MFMA -> syncthreads} structure
// exposed L2 latency on every step (m233's 2-phase stall). Fix: B-fragments
// are contiguous 16B row-slices of Wt[n][k] -> load them DIRECTLY to VGPRs
// with global_load_dwordx4 (weights are L2-resident, re-read by all blocks).
// No Bs, no in-loop barriers (Ts is read-only within a phase); 5 barriers
// total. LDS 48->32 KB. Compiler free to pipeline loads across the fully
// unrolled K-steps.
// Swizzle invariant (Ts only): LDS chunk cs of row holds global chunk
// cs^(row&7); reads XOR the same.
// ============================================================================
template <int K1>
__global__ __launch_bounds__(256, 3)
void fused_mlp_kernel(const unsigned short* __restrict__ A,    // [M][K1]
                      const unsigned short* __restrict__ W1t,  // [256][K1]
                      const float* __restrict__ b1,            // [256]
                      const unsigned short* __restrict__ W2t,  // [256][256]
                      const float* __restrict__ b2,            // [256]
                      unsigned short* __restrict__ H,          // [M][256]
                      int M) {
  constexpr int ACH = K1 / 8;           // 16B chunks per A row (8 or 32)
  constexpr int ZP = (64 * ACH) / 256;  // cp16 issues/thread for Z (2 or 8)

  __shared__ unsigned short Ts[64 * 256];  // 32 KB (Z then T then H-stage)

  const int m0 = blockIdx.x * 64;
  const int tid = threadIdx.x;
  const int lane = tid & 63;
  const int wave = tid >> 6;
  const int fr = lane & 15;
  const int fq = lane >> 4;
  const int wn = wave * 64;

  // ---- stage Z once into Ts (per-lane pre-swizzled global source) ----
#pragma unroll
  for (int p = 0; p < ZP; p++) {
    int slot = p * 256 + tid;
    int row = slot / ACH;
    int cs = slot % ACH;
    int cg = cs ^ (row & 7);
    int grow = m0 + row;
    if (grow >= M) grow = M - 1;
    cp16(A + (size_t)grow * K1 + cg * 8, Ts + (size_t)(p * 256 + wn) * 8);
  }

  // ---- per-lane B row bases (direct global->VGPR fragments) ----
  const unsigned short* wb1[4];
  const unsigned short* wb2[4];
#pragma unroll
  for (int j = 0; j < 4; j++) {
    int n = wn + j * 16 + fr;
    wb1[j] = W1t + (size_t)n * K1 + fq * 8;
    wb2[j] = W2t + (size_t)n * 256 + fq * 8;
  }

  floatx4 acc[4][4];
#pragma unroll
  for (int i = 0; i < 4; i++)
#pragma unroll
    for (int j = 0; j < 4; j++) acc[i][j] = (floatx4){0.f, 0.f, 0.f, 0.f};

  __syncthreads();  // Z staged (compiler drains vmcnt before barrier)

  // ---------------- phase 1: acc = Z @ W1t^T (no barriers) ----------------
#pragma unroll
  for (int k0 = 0; k0 < K1; k0 += 32) {
    shortx8 af[4], bv[4];
    const int kc = k0 >> 3;
#pragma unroll
    for (int j = 0; j < 4; j++) bv[j] = *(const shortx8*)(wb1[j] + k0);
#pragma unroll
    for (int i = 0; i < 4; i++) {
      int row = i * 16 + fr;
      af[i] = *(const shortx8*)&Ts[row * K1 + (((kc + fq) ^ (fr & 7)) << 3)];
    }
#pragma unroll
    for (int i = 0; i < 4; i++)
#pragma unroll
      for (int j = 0; j < 4; j++)
        acc[i][j] = __builtin_amdgcn_mfma_f32_16x16x32_bf16(af[i], bv[j], acc[i][j], 0, 0, 0);
  }
  __syncthreads();  // all waves done reading Ts (Z)

  // ---- T = relu(acc + b1) overwrites Ts ----
#pragma unroll
  for (int j = 0; j < 4; j++) {
    int col = wn + j * 16 + fr;
    float bb = b1[col];
    int cgc = col >> 3, c7 = col & 7;
#pragma unroll
    for (int i = 0; i < 4; i++)
#pragma unroll
      for (int r = 0; r < 4; r++) {
        int row = i * 16 + fq * 4 + r;
        float v = fmaxf(acc[i][j][r] + bb, 0.f);
        Ts[row * 256 + (((cgc ^ (row & 7)) << 3) | c7)] = f2bf(v);
        acc[i][j][r] = 0.f;
      }
  }
  __syncthreads();  // T visible to all waves

  // ---------------- phase 2: acc = T @ W2t^T (no barriers) ----------------
#pragma unroll
  for (int k0 = 0; k0 < 256; k0 += 32) {
    shortx8 af[4], bv[4];
    const int kc = k0 >> 3;
#pragma unroll
    for (int j = 0; j < 4; j++) bv[j] = *(const shortx8*)(wb2[j] + k0);
#pragma unroll
    for (int i = 0; i < 4; i++) {
      int row = i * 16 + fr;
      af[i] = *(const shortx8*)&Ts[row * 256 + (((kc + fq) ^ (fr & 7)) << 3)];
    }
#pragma unroll
    for (int i = 0; i < 4; i++)
#pragma unroll
      for (int j = 0; j < 4; j++)
        acc[i][j] = __builtin_amdgcn_mfma_f32_16x16x32_bf16(af[i], bv[j], acc[i][j], 0, 0, 0);
  }
  __syncthreads();  // all waves done reading Ts (T)

  // ---- epilogue: H = relu(acc + b2), staged via Ts for coalesced stores ----
#pragma unroll
  for (int j = 0; j < 4; j++) {
    int col = wn + j * 16 + fr;
    float bb = b2[col];
    int cgc = col >> 3, c7 = col & 7;
#pragma unroll
    for (int i = 0; i < 4; i++)
#pragma unroll
      for (int r = 0; r < 4; r++) {
        int row = i * 16 + fq * 4 + r;
        float v = fmaxf(acc[i][j][r] + bb, 0.f);
        Ts[row * 256 + (((cgc ^ (row & 7)) << 3) | c7)] = f2bf(v);
      }
  }
  __syncthreads();
  const int r2 = tid >> 5;    // 0..7
  const int cg2 = tid & 31;   // output 16B chunk
#pragma unroll
  for (int p = 0; p < 8; p++) {
    int row = p * 8 + r2;
    int grow = m0 + row;
    if (grow < M) {
      uint4 v = *(const uint4*)&Ts[row * 256 + ((cg2 ^ (row & 7)) << 3)];
      *(uint4*)&H[(size_t)grow * 256 + cg2 * 8] = v;
    }
  }
}

// ============================================================================
// R20: fused layer-2 + task-dot, barrier-free K-loops (same B->VGPR scheme).
// Z staged ONCE (read-only throughout): ONE barrier total. Per-wave col-range
// partials accumulate into nodedot via atomicAdd (R19 fix kept).
// ============================================================================
__global__ __launch_bounds__(256, 3)
void fused_dot_kernel(const unsigned short* __restrict__ A,    // Z [M][256]
                      const unsigned short* __restrict__ W1t,  // [512][256]
                      const float* __restrict__ b1,            // [512]
                      const float* __restrict__ w2v,           // [512]
                      float* __restrict__ nodedot, int M) {
  __shared__ unsigned short Ts[64 * 256];  // 32 KB (Z)

  const int m0 = blockIdx.x * 64;
  const int tid = threadIdx.x;
  const int lane = tid & 63;
  const int wave = tid >> 6;
  const int fr = lane & 15;
  const int fq = lane >> 4;
  const int wn = wave * 64;

#pragma unroll
  for (int p = 0; p < 8; p++) {
    int slot = p * 256 + tid;
    int row = slot >> 5;
    int cs = slot & 31;
    int cg = cs ^ (row & 7);
    int grow = m0 + row;
    if (grow >= M) grow = M - 1;
    cp16(A + (size_t)grow * 256 + cg * 8, Ts + (size_t)(p * 256 + wn) * 8);
  }

  float pd[4][4];
#pragma unroll
  for (int i = 0; i < 4; i++)
#pragma unroll
    for (int r = 0; r < 4; r++) pd[i][r] = 0.f;

  __syncthreads();  // Z staged; Ts read-only from here on

  for (int nh = 0; nh < 2; nh++) {
    const unsigned short* wb[4];
#pragma unroll
    for (int j = 0; j < 4; j++) {
      int n = nh * 256 + wn + j * 16 + fr;
      wb[j] = W1t + (size_t)n * 256 + fq * 8;
    }
    floatx4 acc[4][4];
#pragma unroll
    for (int i = 0; i < 4; i++)
#pragma unroll
      for (int j = 0; j < 4; j++) acc[i][j] = (floatx4){0.f, 0.f, 0.f, 0.f};
#pragma unroll
    for (int k0 = 0; k0 < 256; k0 += 32) {
      shortx8 af[4], bv[4];
      const int kc = k0 >> 3;
#pragma unroll
      for (int j = 0; j < 4; j++) bv[j] = *(const shortx8*)(wb[j] + k0);
#pragma unroll
      for (int i = 0; i < 4; i++) {
        int row = i * 16 + fr;
        af[i] = *(const shortx8*)&Ts[row * 256 + (((kc + fq) ^ (fr & 7)) << 3)];
      }
#pragma unroll
      for (int i = 0; i < 4; i++)
#pragma unroll
        for (int j = 0; j < 4; j++)
          acc[i][j] = __builtin_amdgcn_mfma_f32_16x16x32_bf16(af[i], bv[j], acc[i][j], 0, 0, 0);
    }
#pragma unroll
    for (int j = 0; j < 4; j++) {
      int col = nh * 256 + wn + j * 16 + fr;
      float bb = b1[col];
      float wv = w2v[col];
#pragma unroll
      for (int i = 0; i < 4; i++)
#pragma unroll
        for (int r = 0; r < 4; r++)
          pd[i][r] += fmaxf(acc[i][j][r] + bb, 0.f) * wv;
    }
  }

#pragma unroll
  for (int i = 0; i < 4; i++)
#pragma unroll
    for (int r = 0; r < 4; r++) {
      float s = pd[i][r];
#pragma unroll
      for (int off = 1; off < 16; off <<= 1) s += __shfl_xor(s, off);
      if (fr == 0) {
        int row = m0 + i * 16 + fq * 4 + r;
        // 4 waves hold disjoint col-range partials for the SAME row.
        if (row < M) unsafeAtomicAdd(&nodedot[row], s);
      }
    }
}

// ---------------- readout ----------------------------------------------------
__global__ __launch_bounds__(256)
void pool_kernel(const float* __restrict__ nodedot, const int* __restrict__ batch,
                 float* __restrict__ out, const float* __restrict__ c2p) {
  int t = blockIdx.x * 256 + threadIdx.x;
  int i0 = t * 64;
  if (i0 >= N_NODES) return;
  int i1 = i0 + 64;
  if (i1 > N_NODES) i1 = N_NODES;
  const float c2 = *c2p;
  int g = batch[i0];
  float s = 0.f;
  for (int i = i0; i < i1; i++) {
    int gi = batch[i];
    if (gi != g) { unsafeAtomicAdd(&out[g], s); g = gi; s = 0.f; }
    s += nodedot[i] + c2;
  }
  unsafeAtomicAdd(&out[g], s);
}

extern "C" void kernel_launch(void* const* d_in, const int* in_sizes, int n_in,
                              void* d_out, int out_size, void* d_ws, size_t ws_size,
                              hipStream_t stream) {
  const float* x       = (const float*)d_in[0];
  const int*   ei      = (const int*)d_in[1];
  const int*   batch   = (const int*)d_in[2];
  const float* W_embed = (const float*)d_in[3];
  const float* b_embed = (const float*)d_in[4];
  const float* eps     = (const float*)d_in[5];
  const float* W1[3] = {(const float*)d_in[6],  (const float*)d_in[10], (const float*)d_in[14]};
  const float* B1[3] = {(const float*)d_in[7],  (const float*)d_in[11], (const float*)d_in[15]};
  const float* W2[3] = {(const float*)d_in[8],  (const float*)d_in[12], (const float*)d_in[16]};
  const float* B2[3] = {(const float*)d_in[9],  (const float*)d_in[13], (const float*)d_in[17]};
  const float* W_task = (const float*)d_in[18];
  const float* b_task = (const float*)d_in[19];
  float* out = (float*)d_out;

  const size_t OFF_RZ  = 102400000;
  const size_t OFF_AUX = 153600000;
  if (ws_size < OFF_AUX + 4000000) return;
  unsigned short* RH = (unsigned short*)d_ws;
  unsigned short* RZ = (unsigned short*)((char*)d_ws + OFF_RZ);
  char* aux = (char*)d_ws + OFF_AUX;
  int* row_ptr  = (int*)(aux);               // 100001 ints
  int* cursor   = (int*)(aux + 400016);      // 100000 ints (also deg histogram)
  int* csr_src  = (int*)(aux + 800016);      // 300000 ints
  int* blk_sums = (int*)(aux + 2000016);     // 98 ints
  int* blk_off  = (int*)(aux + 2000416);     // 98 ints
  float* nodedot = (float*)(aux + 2000816);  // 100000 floats
  unsigned short* WT = (unsigned short*)(aux + 2400832);  // 360448 bf16
  float* w2v = (float*)(aux + 3200832);      // 512 floats
  float* c2  = (float*)(aux + 3202880);      // 1 float
  unsigned short* WfT    = WT;
  unsigned short* Wt2_0  = WT + 32768;
  unsigned short* Wt1_1  = WT + 98304;
  unsigned short* Wt2_1  = WT + 163840;
  unsigned short* Wt1_2  = WT + 229376;

  // ---- prep: all independent prologue work (1 dispatch) ----
  PrepArgs pa;
  pa.W[0] = W2[0]; pa.Wt[0] = Wt2_0; pa.K[0] = 256; pa.N[0] = 256;
  pa.W[1] = W1[1]; pa.Wt[1] = Wt1_1; pa.K[1] = 256; pa.N[1] = 256;
  pa.W[2] = W2[1]; pa.Wt[2] = Wt2_1; pa.K[2] = 256; pa.N[2] = 256;
  pa.W[3] = W1[2]; pa.Wt[3] = Wt1_2; pa.K[3] = 256; pa.N[3] = 512;
  pa.We = W_embed; pa.be = b_embed; pa.W1_0 = W1[0]; pa.WfT = WfT;
  pa.W2_2 = W2[2]; pa.b2_2 = B2[2]; pa.wtask = W_task; pa.w2v = w2v; pa.c2 = c2;
  pa.nodedot = nodedot; pa.out = out; pa.b_task = b_task;
  prep_kernel<<<889, 256, 0, stream>>>(pa);

  // ---- CSR build ----
  zero_kernel<<<(N_NODES + 255) / 256, 256, 0, stream>>>(cursor, N_NODES);
  hist_kernel<<<(E_EDGES + 255) / 256, 256, 0, stream>>>(ei, cursor);
  scan_blk_kernel<<<98, 256, 0, stream>>>(cursor, row_ptr, blk_sums, N_NODES, N_NODES + 1);
  scan_blk_kernel<<<1, 256, 0, stream>>>(blk_sums, blk_off, nullptr, 98, 98);
  scan_fix_kernel<<<(N_NODES + 256) / 256, 256, 0, stream>>>(row_ptr, blk_off, cursor);
  fill_kernel<<<(E_EDGES + 255) / 256, 256, 0, stream>>>(ei, cursor, csr_src);

  const int FB = (N_NODES + 63) / 64;  // 1563 fused blocks (64 rows each)

  // ---- layer 0 (folded embed): G -> H = relu(relu(G@WfT^T+b1)@W2_0+b2) ----
  gatherx_kernel<<<N_NODES / 4, 256, 0, stream>>>(x, RZ, row_ptr, csr_src, eps);
  fused_mlp_kernel<64><<<FB, 256, 0, stream>>>(RZ, WfT, B1[0], Wt2_0, B2[0], RH, N_NODES);

  // ---- layer 1 ----
  gather_kernel<<<N_NODES / 4, 256, 0, stream>>>(RH, RZ, row_ptr, csr_src, eps, 1);
  fused_mlp_kernel<256><<<FB, 256, 0, stream>>>(RZ, Wt1_1, B1[1], Wt2_1, B2[1], RH, N_NODES);

  // ---- layer 2: gather, then fused GEMM + task-dot ----
  gather_kernel<<<N_NODES / 4, 256, 0, stream>>>(RH, RZ, row_ptr, csr_src, eps, 2);
  fused_dot_kernel<<<FB, 256, 0, stream>>>(RZ, Wt1_2, B1[2], w2v, nodedot, N_NODES);

  // ---- out[g] = b_task + sum_i (nodedot_i + c2) ----
  pool_kernel<<<((N_NODES + 63) / 64 + 255) / 256, 256, 0, stream>>>(nodedot, batch, out, c2);
}

// Round 5
// 464.911 us; speedup vs baseline: 1.1196x; 1.1196x over previous
//
#include <hip/hip_runtime.h>

#define N_NODES 100000
#define E_EDGES 300000
#define N_GRAPHS 2048

typedef float  floatx4 __attribute__((ext_vector_type(4)));
typedef short  shortx8 __attribute__((ext_vector_type(8)));

__device__ __forceinline__ float bf2f(unsigned short u) {
  return __uint_as_float(((unsigned int)u) << 16);
}
__device__ __forceinline__ unsigned short f2bf(float f) {
  unsigned int u = __float_as_uint(f);
  u += 0x7FFFu + ((u >> 16) & 1u);
  return (unsigned short)(u >> 16);
}

// async global->LDS, 16B per lane; lds base wave-uniform, dst = base+lane*16 (m104)
__device__ __forceinline__ void cp16(const void* g, void* l) {
  __builtin_amdgcn_global_load_lds(
      (const __attribute__((address_space(1))) unsigned int*)g,
      (__attribute__((address_space(3))) unsigned int*)l, 16, 0, 0);
}

// ---- prep kernel: all independent prologue work in ONE dispatch -------------
struct PrepArgs {
  const float* W[4];
  unsigned short* Wt[4];
  int K[4];
  int N[4];
  const float* We;
  const float* be;
  const float* W1_0;
  unsigned short* WfT;
  const float* W2_2;
  const float* b2_2;
  const float* wtask;
  float* w2v;
  float* c2;
  float* nodedot;
  float* out;
  const float* b_task;
};

__global__ __launch_bounds__(256)
void prep_kernel(PrepArgs a) {
  const int blk = blockIdx.x;
  if (blk < 320) {
    int z, b;
    if (blk < 64)       { z = 0; b = blk; }
    else if (blk < 128) { z = 1; b = blk - 64; }
    else if (blk < 192) { z = 2; b = blk - 128; }
    else                { z = 3; b = blk - 192; }
    const int K = a.K[z], N = a.N[z];
    const int nt = N / 32;
    const int kb = (b / nt) * 32, nb = (b % nt) * 32;
    __shared__ unsigned short tile[32][33];
    const float* W = a.W[z];
    unsigned short* Wt = a.Wt[z];
    const int tx = threadIdx.x & 31, ty = threadIdx.x >> 5;
    for (int r = ty; r < 32; r += 8)
      tile[r][tx] = f2bf(W[(size_t)(kb + r) * N + nb + tx]);
    __syncthreads();
    for (int r = ty; r < 32; r += 8)
      Wt[(size_t)(nb + r) * K + kb + tx] = tile[tx][r];
  } else if (blk < 361) {
    const int k = blk - 320;  // 0..40
    const int n = threadIdx.x;
    if (k < 40) {
      float s = 0.f;
      for (int j = 0; j < 128; j++) s = fmaf(a.We[k * 128 + j], a.W1_0[(size_t)j * 256 + n], s);
      a.WfT[n * 64 + k] = f2bf(s);
    } else {
      float s = 0.f;
      for (int j = 0; j < 128; j++) s = fmaf(a.be[j], a.W1_0[(size_t)j * 256 + n], s);
      a.WfT[n * 64 + 40] = f2bf(s);
      for (int kk = 41; kk < 64; kk++) a.WfT[n * 64 + kk] = 0;
    }
  } else if (blk < 490) {
    const int p = blk - 361;  // 0..128
    const int lane = threadIdx.x & 63;
    const int wave = threadIdx.x >> 6;
    if (p < 128) {
      const int k = p * 4 + wave;
      const float* row = a.W2_2 + (size_t)k * 512 + lane * 8;
      float4 a0 = *(const float4*)(row);
      float4 a1 = *(const float4*)(row + 4);
      float4 w0 = *(const float4*)(a.wtask + lane * 8);
      float4 w1 = *(const float4*)(a.wtask + lane * 8 + 4);
      float s = a0.x * w0.x + a0.y * w0.y + a0.z * w0.z + a0.w * w0.w +
                a1.x * w1.x + a1.y * w1.y + a1.z * w1.z + a1.w * w1.w;
#pragma unroll
      for (int off = 32; off > 0; off >>= 1) s += __shfl_down(s, off);
      if (lane == 0) a.w2v[k] = s;
    } else if (wave == 0) {
      float4 a0 = *(const float4*)(a.b2_2 + lane * 8);
      float4 a1 = *(const float4*)(a.b2_2 + lane * 8 + 4);
      float4 w0 = *(const float4*)(a.wtask + lane * 8);
      float4 w1 = *(const float4*)(a.wtask + lane * 8 + 4);
      float s = a0.x * w0.x + a0.y * w0.y + a0.z * w0.z + a0.w * w0.w +
                a1.x * w1.x + a1.y * w1.y + a1.z * w1.z + a1.w * w1.w;
#pragma unroll
      for (int off = 32; off > 0; off >>= 1) s += __shfl_down(s, off);
      if (lane == 0) *a.c2 = s;
    }
  } else if (blk < 881) {
    int i = (blk - 490) * 256 + threadIdx.x;
    if (i < N_NODES) a.nodedot[i] = 0.f;
  } else {
    int g = (blk - 881) * 256 + threadIdx.x;
    if (g < N_GRAPHS) a.out[g] = a.b_task[0];
  }
}

// ---------------- CSR build: zero, histogram, scan, fill ---------------------
__global__ __launch_bounds__(256)
void zero_kernel(int* __restrict__ p, int n) {
  int i = blockIdx.x * 256 + threadIdx.x;
  if (i < n) p[i] = 0;
}

__global__ __launch_bounds__(256)
void hist_kernel(const int* __restrict__ ei, int* __restrict__ deg) {
  int e = blockIdx.x * 256 + threadIdx.x;
  if (e < E_EDGES) atomicAdd(&deg[ei[E_EDGES + e]], 1);
}

__global__ __launch_bounds__(256)
void scan_blk_kernel(const int* __restrict__ in, int* __restrict__ out,
                     int* __restrict__ blk_sums, int n_in, int n_out) {
  __shared__ int sm[256];
  const int t = threadIdx.x;
  const int base = blockIdx.x * 1024 + t * 4;
  int d0 = (base + 0 < n_in) ? in[base + 0] : 0;
  int d1 = (base + 1 < n_in) ? in[base + 1] : 0;
  int d2 = (base + 2 < n_in) ? in[base + 2] : 0;
  int d3 = (base + 3 < n_in) ? in[base + 3] : 0;
  int s = d0 + d1 + d2 + d3;
  sm[t] = s;
  __syncthreads();
  for (int off = 1; off < 256; off <<= 1) {
    int v = (t >= off) ? sm[t - off] : 0;
    __syncthreads();
    sm[t] += v;
    __syncthreads();
  }
  int excl = sm[t] - s;
  if (base + 0 < n_out) out[base + 0] = excl;
  if (base + 1 < n_out) out[base + 1] = excl + d0;
  if (base + 2 < n_out) out[base + 2] = excl + d0 + d1;
  if (base + 3 < n_out) out[base + 3] = excl + d0 + d1 + d2;
  if (t == 255 && blk_sums) blk_sums[blockIdx.x] = sm[255];
}

__global__ __launch_bounds__(256)
void scan_fix_kernel(int* __restrict__ row_ptr, const int* __restrict__ blk_off,
                     int* __restrict__ cursor) {
  int i = blockIdx.x * 256 + threadIdx.x;
  if (i <= N_NODES) {
    int v = row_ptr[i] + blk_off[i >> 10];
    row_ptr[i] = v;
    if (i < N_NODES) cursor[i] = v;
  }
}

__global__ __launch_bounds__(256)
void fill_kernel(const int* __restrict__ ei, int* __restrict__ cursor,
                 int* __restrict__ csr_src) {
  int e = blockIdx.x * 256 + threadIdx.x;
  if (e < E_EDGES) {
    int d = ei[E_EDGES + e];
    int slot = atomicAdd(&cursor[d], 1);
    csr_src[slot] = ei[e];
  }
}

// ---- gatherx: G[n,64] = bf16([(1+eps)X_n + sum X_src | f_n | 0...]) ---------
__global__ __launch_bounds__(256)
void gatherx_kernel(const float* __restrict__ X, unsigned short* __restrict__ G,
                    const int* __restrict__ row_ptr, const int* __restrict__ csr,
                    const float* __restrict__ eps) {
  const int node = blockIdx.x * 4 + (threadIdx.x >> 6);
  const int lane = threadIdx.x & 63;
  const float sc = 1.0f + eps[0];
  const int e0 = row_ptr[node];
  const int e1 = row_ptr[node + 1];
  float acc = 0.f;
  if (lane < 40) {
    acc = sc * X[(size_t)node * 40 + lane];
    int e = e0;
    for (; e + 4 <= e1; e += 4) {
      int s0 = csr[e], s1 = csr[e + 1], s2 = csr[e + 2], s3 = csr[e + 3];
      float a0 = X[(size_t)s0 * 40 + lane];
      float a1 = X[(size_t)s1 * 40 + lane];
      float a2 = X[(size_t)s2 * 40 + lane];
      float a3 = X[(size_t)s3 * 40 + lane];
      acc += (a0 + a1) + (a2 + a3);
    }
    for (; e < e1; e++)
      acc += X[(size_t)csr[e] * 40 + lane];
  } else if (lane == 40) {
    acc = sc + (float)(e1 - e0);
  }
  G[(size_t)node * 64 + lane] = f2bf(acc);
}

// ------- gather (D=256): Z[d] = bf16((1+eps)*H[d] + sum H[src]) --------------
// R14 exact form: ONE wave per node, uint2 (8B) loads, simple loop.
__global__ __launch_bounds__(256)
void gather_kernel(const unsigned short* __restrict__ H, unsigned short* __restrict__ Z,
                   const int* __restrict__ row_ptr, const int* __restrict__ csr,
                   const float* __restrict__ eps, int l) {
  const int node = blockIdx.x * 4 + (threadIdx.x >> 6);
  const int lane = threadIdx.x & 63;
  const float sc = 1.0f + eps[l];
  uint2 hv = *(const uint2*)(H + (size_t)node * 256 + lane * 4);
  float acc[4];
  acc[0] = sc * bf2f((unsigned short)(hv.x & 0xFFFF));
  acc[1] = sc * bf2f((unsigned short)(hv.x >> 16));
  acc[2] = sc * bf2f((unsigned short)(hv.y & 0xFFFF));
  acc[3] = sc * bf2f((unsigned short)(hv.y >> 16));
  const int e0 = row_ptr[node];
  const int e1 = row_ptr[node + 1];
  int e = e0;
  for (; e + 2 <= e1; e += 2) {
    int s0 = csr[e], s1 = csr[e + 1];
    uint2 a = *(const uint2*)(H + (size_t)s0 * 256 + lane * 4);
    uint2 b = *(const uint2*)(H + (size_t)s1 * 256 + lane * 4);
    acc[0] += bf2f((unsigned short)(a.x & 0xFFFF)) + bf2f((unsigned short)(b.x & 0xFFFF));
    acc[1] += bf2f((unsigned short)(a.x >> 16))    + bf2f((unsigned short)(b.x >> 16));
    acc[2] += bf2f((unsigned short)(a.y & 0xFFFF)) + bf2f((unsigned short)(b.y & 0xFFFF));
    acc[3] += bf2f((unsigned short)(a.y >> 16))    + bf2f((unsigned short)(b.y >> 16));
  }
  if (e < e1) {
    int s0 = csr[e];
    uint2 a = *(const uint2*)(H + (size_t)s0 * 256 + lane * 4);
    acc[0] += bf2f((unsigned short)(a.x & 0xFFFF));
    acc[1] += bf2f((unsigned short)(a.x >> 16));
    acc[2] += bf2f((unsigned short)(a.y & 0xFFFF));
    acc[3] += bf2f((unsigned short)(a.y >> 16));
  }
  unsigned short z[4] = {f2bf(acc[0]), f2bf(acc[1]), f2bf(acc[2]), f2bf(acc[3])};
  *(uint2*)(Z + (size_t)node * 256 + lane * 4) = *(uint2*)z;
}

// ============================================================================
// R21: fused per-layer MLP = R19 verified structure + minimum 2-phase pipeline
// (catalog T3-min, m230/m248): per K-step {stage panel t+1 -> Bs[buf^1];
// ds_read panel t; MFMA; ONE __syncthreads}. The barrier's vmcnt(0) drain now
// comes AFTER compute, so the W-panel L2 latency hides under the MFMA phase
// (R19 drained vmcnt BEFORE the reads every step -> m233's 2-phase stall,
// MfmaUtil 14%). Double-buffered Bs: 2x16KB + Ts 32KB = 64KB -> 2 blocks/CU
// (= R19's measured 26% occupancy anyway). Race-clean: Bs[buf^1] was last
// read two barriers ago. Cross-phase prefetch: last phase-1 step stages W2
// panel 0.
// Swizzle invariants unchanged from R19 (verified): Ts chunk cs of row holds
// global chunk cs^(row&7); Bs slot holds W chunk bc^((n>>1)&3).
// ============================================================================
template <int K1>
__global__ __launch_bounds__(256, 2)
void fused_mlp_kernel(const unsigned short* __restrict__ A,    // [M][K1]
                      const unsigned short* __restrict__ W1t,  // [256][K1]
                      const float* __restrict__ b1,            // [256]
                      const unsigned short* __restrict__ W2t,  // [256][256]
                      const float* __restrict__ b2,            // [256]
                      unsigned short* __restrict__ H,          // [M][256]
                      int M) {
  constexpr int ACH = K1 / 8;           // 16B chunks per A row (8 or 32)
  constexpr int ZP = (64 * ACH) / 256;  // cp16 issues/thread for Z (2 or 8)
  constexpr int NT1 = K1 / 32;          // phase-1 K-steps (2 or 8)

  __shared__ unsigned short Bs[2][256 * 32];  // 2 x 16 KB W-panel dbuf
  __shared__ unsigned short Ts[64 * 256];     // 32 KB (Z then T then H-stage)

  const int m0 = blockIdx.x * 64;
  const int tid = threadIdx.x;
  const int lane = tid & 63;
  const int wave = tid >> 6;
  const int fr = lane & 15;
  const int fq = lane >> 4;
  const int wn = wave * 64;

  // ---- stage Z once into Ts (per-lane pre-swizzled global source) ----
#pragma unroll
  for (int p = 0; p < ZP; p++) {
    int slot = p * 256 + tid;
    int row = slot / ACH;
    int cs = slot % ACH;
    int cg = cs ^ (row & 7);
    int grow = m0 + row;
    if (grow >= M) grow = M - 1;
    cp16(A + (size_t)grow * K1 + cg * 8, Ts + (size_t)(p * 256 + wn) * 8);
  }

  // ---- B staging source pointers (pre-swizzled, R19-verified) ----
  const int bn_ = tid >> 2;
  const int bc_ = tid & 3;
  const unsigned short* srcW1[4];
  const unsigned short* srcW2[4];
#pragma unroll
  for (int p = 0; p < 4; p++) {
    int n = p * 64 + bn_;
    int sw = (bc_ ^ ((n >> 1) & 3)) << 3;
    srcW1[p] = W1t + (size_t)n * K1 + sw;
    srcW2[p] = W2t + (size_t)n * 256 + sw;
  }

  // ---- B-frag LDS offsets (constant across K-steps) ----
  int offB[4];
#pragma unroll
  for (int j = 0; j < 4; j++) {
    int n = wn + j * 16 + fr;
    offB[j] = n * 32 + ((fq ^ ((n >> 1) & 3)) << 3);
  }

  // ---- stage W1 panel 0 into Bs[0] ----
#pragma unroll
  for (int p = 0; p < 4; p++)
    cp16(srcW1[p], &Bs[0][(size_t)(p * 256 + wn) * 8]);

  floatx4 acc[4][4];
#pragma unroll
  for (int i = 0; i < 4; i++)
#pragma unroll
    for (int j = 0; j < 4; j++) acc[i][j] = (floatx4){0.f, 0.f, 0.f, 0.f};

  __syncthreads();  // Z + W1 panel 0 staged & visible
  int buf = 0;

  // ---------------- phase 1: acc = Z @ W1t^T ----------------
  for (int t = 0; t < NT1; t++) {
    // prefetch next panel (last step prefetches W2 panel 0)
    if (t + 1 < NT1) {
#pragma unroll
      for (int p = 0; p < 4; p++)
        cp16(srcW1[p] + (t + 1) * 32, &Bs[buf ^ 1][(size_t)(p * 256 + wn) * 8]);
    } else {
#pragma unroll
      for (int p = 0; p < 4; p++)
        cp16(srcW2[p], &Bs[buf ^ 1][(size_t)(p * 256 + wn) * 8]);
    }
    shortx8 af[4], bv[4];
    const int kc = t * 4;
#pragma unroll
    for (int i = 0; i < 4; i++) {
      int row = i * 16 + fr;
      af[i] = *(const shortx8*)&Ts[row * K1 + (((kc + fq) ^ (fr & 7)) << 3)];
    }
#pragma unroll
    for (int j = 0; j < 4; j++) bv[j] = *(const shortx8*)&Bs[buf][offB[j]];
#pragma unroll
    for (int i = 0; i < 4; i++)
#pragma unroll
      for (int j = 0; j < 4; j++)
        acc[i][j] = __builtin_amdgcn_mfma_f32_16x16x32_bf16(af[i], bv[j], acc[i][j], 0, 0, 0);
    __syncthreads();  // drains prefetch (after compute) + orders buffer reuse
    buf ^= 1;
  }

  // ---- T = relu(acc + b1) overwrites Ts (all Ts reads done: loop-end sync) --
#pragma unroll
  for (int j = 0; j < 4; j++) {
    int col = wn + j * 16 + fr;
    float bb = b1[col];
    int cgc = col >> 3, c7 = col & 7;
#pragma unroll
    for (int i = 0; i < 4; i++)
#pragma unroll
      for (int r = 0; r < 4; r++) {
        int row = i * 16 + fq * 4 + r;
        float v = fmaxf(acc[i][j][r] + bb, 0.f);
        Ts[row * 256 + (((cgc ^ (row & 7)) << 3) | c7)] = f2bf(v);
        acc[i][j][r] = 0.f;
      }
  }
  __syncthreads();  // T visible; Bs[buf] holds W2 panel 0

  // ---------------- phase 2: acc = T @ W2t^T ----------------
  for (int t = 0; t < 8; t++) {
    if (t + 1 < 8) {
#pragma unroll
      for (int p = 0; p < 4; p++)
        cp16(srcW2[p] + (t + 1) * 32, &Bs[buf ^ 1][(size_t)(p * 256 + wn) * 8]);
    }
    shortx8 af[4], bv[4];
    const int kc = t * 4;
#pragma unroll
    for (int i = 0; i < 4; i++) {
      int row = i * 16 + fr;
      af[i] = *(const shortx8*)&Ts[row * 256 + (((kc + fq) ^ (fr & 7)) << 3)];
    }
#pragma unroll
    for (int j = 0; j < 4; j++) bv[j] = *(const shortx8*)&Bs[buf][offB[j]];
#pragma unroll
    for (int i = 0; i < 4; i++)
#pragma unroll
      for (int j = 0; j < 4; j++)
        acc[i][j] = __builtin_amdgcn_mfma_f32_16x16x32_bf16(af[i], bv[j], acc[i][j], 0, 0, 0);
    __syncthreads();
    buf ^= 1;
  }

  // ---- epilogue: H = relu(acc + b2), staged via Ts for coalesced stores ----
#pragma unroll
  for (int j = 0; j < 4; j++) {
    int col = wn + j * 16 + fr;
    float bb = b2[col];
    int cgc = col >> 3, c7 = col & 7;
#pragma unroll
    for (int i = 0; i < 4; i++)
#pragma unroll
      for (int r = 0; r < 4; r++) {
        int row = i * 16 + fq * 4 + r;
        float v = fmaxf(acc[i][j][r] + bb, 0.f);
        Ts[row * 256 + (((cgc ^ (row & 7)) << 3) | c7)] = f2bf(v);
      }
  }
  __syncthreads();
  const int r2 = tid >> 5;    // 0..7
  const int cg2 = tid & 31;   // output 16B chunk
#pragma unroll
  for (int p = 0; p < 8; p++) {
    int row = p * 8 + r2;
    int grow = m0 + row;
    if (grow < M) {
      uint4 v = *(const uint4*)&Ts[row * 256 + ((cg2 ^ (row & 7)) << 3)];
      *(uint4*)&H[(size_t)grow * 256 + cg2 * 8] = v;
    }
  }
}

// ============================================================================
// R21: fused layer-2 + task-dot with the same 2-phase pipeline (16 flattened
// K-steps over the two 256-col halves; cross-half prefetch at step 7).
// Output change: per-wave partials -> nodedot4[wave][row] via PLAIN stores
// (each row owned by one block; 4 planes summed in pool). Removes the 400K
// device-scope atomics that are the prime suspect for R20's 189 MB
// WRITE_SIZE anomaly.
// ============================================================================
__global__ __launch_bounds__(256, 2)
void fused_dot_kernel(const unsigned short* __restrict__ A,    // Z [M][256]
                      const unsigned short* __restrict__ W1t,  // [512][256]
                      const float* __restrict__ b1,            // [512]
                      const float* __restrict__ w2v,           // [512]
                      float* __restrict__ nodedot4, int M) {
  __shared__ unsigned short Bs[2][256 * 32];  // 2 x 16 KB
  __shared__ unsigned short Ts[64 * 256];     // 32 KB (Z)

  const int m0 = blockIdx.x * 64;
  const int tid = threadIdx.x;
  const int lane = tid & 63;
  const int wave = tid >> 6;
  const int fr = lane & 15;
  const int fq = lane >> 4;
  const int wn = wave * 64;

#pragma unroll
  for (int p = 0; p < 8; p++) {
    int slot = p * 256 + tid;
    int row = slot >> 5;
    int cs = slot & 31;
    int cg = cs ^ (row & 7);
    int grow = m0 + row;
    if (grow >= M) grow = M - 1;
    cp16(A + (size_t)grow * 256 + cg * 8, Ts + (size_t)(p * 256 + wn) * 8);
  }

  const int bn_ = tid >> 2;
  const int bc_ = tid & 3;
  const unsigned short* srcW[4];
#pragma unroll
  for (int p = 0; p < 4; p++) {
    int n = p * 64 + bn_;
    srcW[p] = W1t + (size_t)n * 256 + ((bc_ ^ ((n >> 1) & 3)) << 3);
  }
  int offB[4];
#pragma unroll
  for (int j = 0; j < 4; j++) {
    int n = wn + j * 16 + fr;
    offB[j] = n * 32 + ((fq ^ ((n >> 1) & 3)) << 3);
  }

  // stage W panel for step 0 (nh=0, k0=0)
#pragma unroll
  for (int p = 0; p < 4; p++)
    cp16(srcW[p], &Bs[0][(size_t)(p * 256 + wn) * 8]);

  float pd[4][4];
#pragma unroll
  for (int i = 0; i < 4; i++)
#pragma unroll
    for (int r = 0; r < 4; r++) pd[i][r] = 0.f;

  floatx4 acc[4][4];
#pragma unroll
  for (int i = 0; i < 4; i++)
#pragma unroll
    for (int j = 0; j < 4; j++) acc[i][j] = (floatx4){0.f, 0.f, 0.f, 0.f};

  __syncthreads();  // Z + panel 0 staged
  int buf = 0;

  // 16 flattened K-steps: s = nh*8 + t; panel offset = nh*65536 + t*32
  for (int s = 0; s < 16; s++) {
    int ns = s + 1;
    if (ns < 16) {
      const size_t off = (size_t)(ns >> 3) * 65536 + (size_t)(ns & 7) * 32;
#pragma unroll
      for (int p = 0; p < 4; p++)
        cp16(srcW[p] + off, &Bs[buf ^ 1][(size_t)(p * 256 + wn) * 8]);
    }
    shortx8 af[4], bv[4];
    const int kc = (s & 7) * 4;
#pragma unroll
    for (int i = 0; i < 4; i++) {
      int row = i * 16 + fr;
      af[i] = *(const shortx8*)&Ts[row * 256 + (((kc + fq) ^ (fr & 7)) << 3)];
    }
#pragma unroll
    for (int j = 0; j < 4; j++) bv[j] = *(const shortx8*)&Bs[buf][offB[j]];
#pragma unroll
    for (int i = 0; i < 4; i++)
#pragma unroll
      for (int j = 0; j < 4; j++)
        acc[i][j] = __builtin_amdgcn_mfma_f32_16x16x32_bf16(af[i], bv[j], acc[i][j], 0, 0, 0);
    __syncthreads();
    buf ^= 1;

    if ((s & 7) == 7) {  // end of a 256-col half: fold into pd, reset acc
      const int nh = s >> 3;
#pragma unroll
      for (int j = 0; j < 4; j++) {
        int col = nh * 256 + wn + j * 16 + fr;
        float bb = b1[col];
        float wv = w2v[col];
#pragma unroll
        for (int i = 0; i < 4; i++)
#pragma unroll
          for (int r = 0; r < 4; r++) {
            pd[i][r] += fmaxf(acc[i][j][r] + bb, 0.f) * wv;
            acc[i][j][r] = 0.f;
          }
      }
    }
  }

#pragma unroll
  for (int i = 0; i < 4; i++)
#pragma unroll
    for (int r = 0; r < 4; r++) {
      float s = pd[i][r];
#pragma unroll
      for (int off = 1; off < 16; off <<= 1) s += __shfl_xor(s, off);
      if (fr == 0) {
        int row = m0 + i * 16 + fq * 4 + r;
        // plain store: plane `wave`, row owned by exactly this block
        if (row < M) nodedot4[(size_t)wave * N_NODES + row] = s;
      }
    }
}

// ---------------- readout ----------------------------------------------------
__global__ __launch_bounds__(256)
void pool_kernel(const float* __restrict__ nodedot4, const int* __restrict__ batch,
                 float* __restrict__ out, const float* __restrict__ c2p) {
  int t = blockIdx.x * 256 + threadIdx.x;
  int i0 = t * 64;
  if (i0 >= N_NODES) return;
  int i1 = i0 + 64;
  if (i1 > N_NODES) i1 = N_NODES;
  const float c2 = *c2p;
  int g = batch[i0];
  float s = 0.f;
  for (int i = i0; i < i1; i++) {
    int gi = batch[i];
    if (gi != g) { unsafeAtomicAdd(&out[g], s); g = gi; s = 0.f; }
    float nd = (nodedot4[i] + nodedot4[N_NODES + i]) +
               (nodedot4[2 * N_NODES + i] + nodedot4[3 * N_NODES + i]);
    s += nd + c2;
  }
  unsafeAtomicAdd(&out[g], s);
}

extern "C" void kernel_launch(void* const* d_in, const int* in_sizes, int n_in,
                              void* d_out, int out_size, void* d_ws, size_t ws_size,
                              hipStream_t stream) {
  const float* x       = (const float*)d_in[0];
  const int*   ei      = (const int*)d_in[1];
  const int*   batch   = (const int*)d_in[2];
  const float* W_embed = (const float*)d_in[3];
  const float* b_embed = (const float*)d_in[4];
  const float* eps     = (const float*)d_in[5];
  const float* W1[3] = {(const float*)d_in[6],  (const float*)d_in[10], (const float*)d_in[14]};
  const float* B1[3] = {(const float*)d_in[7],  (const float*)d_in[11], (const float*)d_in[15]};
  const float* W2[3] = {(const float*)d_in[8],  (const float*)d_in[12], (const float*)d_in[16]};
  const float* B2[3] = {(const float*)d_in[9],  (const float*)d_in[13], (const float*)d_in[17]};
  const float* W_task = (const float*)d_in[18];
  const float* b_task = (const float*)d_in[19];
  float* out = (float*)d_out;

  const size_t OFF_ND4 = 51200000;   // old RB region, free since R18: 4x100000 floats
  const size_t OFF_RZ  = 102400000;
  const size_t OFF_AUX = 153600000;
  if (ws_size < OFF_AUX + 4000000) return;
  unsigned short* RH = (unsigned short*)d_ws;
  float* nodedot4 = (float*)((char*)d_ws + OFF_ND4);
  unsigned short* RZ = (unsigned short*)((char*)d_ws + OFF_RZ);
  char* aux = (char*)d_ws + OFF_AUX;
  int* row_ptr  = (int*)(aux);               // 100001 ints
  int* cursor   = (int*)(aux + 400016);      // 100000 ints (also deg histogram)
  int* csr_src  = (int*)(aux + 800016);      // 300000 ints
  int* blk_sums = (int*)(aux + 2000016);     // 98 ints
  int* blk_off  = (int*)(aux + 2000416);     // 98 ints
  float* nodedot = (float*)(aux + 2000816);  // 100000 floats (legacy zero, unused)
  unsigned short* WT = (unsigned short*)(aux + 2400832);  // 360448 bf16
  float* w2v = (float*)(aux + 3200832);      // 512 floats
  float* c2  = (float*)(aux + 3202880);      // 1 float
  unsigned short* WfT    = WT;
  unsigned short* Wt2_0  = WT + 32768;
  unsigned short* Wt1_1  = WT + 98304;
  unsigned short* Wt2_1  = WT + 163840;
  unsigned short* Wt1_2  = WT + 229376;

  // ---- prep: all independent prologue work (1 dispatch) ----
  PrepArgs pa;
  pa.W[0] = W2[0]; pa.Wt[0] = Wt2_0; pa.K[0] = 256; pa.N[0] = 256;
  pa.W[1] = W1[1]; pa.Wt[1] = Wt1_1; pa.K[1] = 256; pa.N[1] = 256;
  pa.W[2] = W2[1]; pa.Wt[2] = Wt2_1; pa.K[2] = 256; pa.N[2] = 256;
  pa.W[3] = W1[2]; pa.Wt[3] = Wt1_2; pa.K[3] = 256; pa.N[3] = 512;
  pa.We = W_embed; pa.be = b_embed; pa.W1_0 = W1[0]; pa.WfT = WfT;
  pa.W2_2 = W2[2]; pa.b2_2 = B2[2]; pa.wtask = W_task; pa.w2v = w2v; pa.c2 = c2;
  pa.nodedot = nodedot; pa.out = out; pa.b_task = b_task;
  prep_kernel<<<889, 256, 0, stream>>>(pa);

  // ---- CSR build ----
  zero_kernel<<<(N_NODES + 255) / 256, 256, 0, stream>>>(cursor, N_NODES);
  hist_kernel<<<(E_EDGES + 255) / 256, 256, 0, stream>>>(ei, cursor);
  scan_blk_kernel<<<98, 256, 0, stream>>>(cursor, row_ptr, blk_sums, N_NODES, N_NODES + 1);
  scan_blk_kernel<<<1, 256, 0, stream>>>(blk_sums, blk_off, nullptr, 98, 98);
  scan_fix_kernel<<<(N_NODES + 256) / 256, 256, 0, stream>>>(row_ptr, blk_off, cursor);
  fill_kernel<<<(E_EDGES + 255) / 256, 256, 0, stream>>>(ei, cursor, csr_src);

  const int FB = (N_NODES + 63) / 64;  // 1563 fused blocks (64 rows each)

  // ---- layer 0 (folded embed): G -> H = relu(relu(G@WfT^T+b1)@W2_0+b2) ----
  gatherx_kernel<<<N_NODES / 4, 256, 0, stream>>>(x, RZ, row_ptr, csr_src, eps);
  fused_mlp_kernel<64><<<FB, 256, 0, stream>>>(RZ, WfT, B1[0], Wt2_0, B2[0], RH, N_NODES);

  // ---- layer 1 ----
  gather_kernel<<<N_NODES / 4, 256, 0, stream>>>(RH, RZ, row_ptr, csr_src, eps, 1);
  fused_mlp_kernel<256><<<FB, 256, 0, stream>>>(RZ, Wt1_1, B1[1], Wt2_1, B2[1], RH, N_NODES);

  // ---- layer 2: gather, then fused GEMM + task-dot ----
  gather_kernel<<<N_NODES / 4, 256, 0, stream>>>(RH, RZ, row_ptr, csr_src, eps, 2);
  fused_dot_kernel<<<FB, 256, 0, stream>>>(RZ, Wt1_2, B1[2], w2v, nodedot4, N_NODES);

  // ---- out[g] = b_task + sum_i (sum_w nodedot4[w][i] + c2) ----
  pool_kernel<<<((N_NODES + 63) / 64 + 255) / 256, 256, 0, stream>>>(nodedot4, batch, out, c2);
}

// Round 6
// 394.128 us; speedup vs baseline: 1.3206x; 1.1796x over previous
//
#include <hip/hip_runtime.h>

#define N_NODES 100000
#define E_EDGES 300000
#define N_GRAPHS 2048

typedef float  floatx4 __attribute__((ext_vector_type(4)));
typedef short  shortx8 __attribute__((ext_vector_type(8)));

__device__ __forceinline__ float bf2f(unsigned short u) {
  return __uint_as_float(((unsigned int)u) << 16);
}
__device__ __forceinline__ unsigned short f2bf(float f) {
  unsigned int u = __float_as_uint(f);
  u += 0x7FFFu + ((u >> 16) & 1u);
  return (unsigned short)(u >> 16);
}

// async global->LDS, 16B per lane; lds base wave-uniform, dst = base+lane*16 (m104)
__device__ __forceinline__ void cp16(const void* g, void* l) {
  __builtin_amdgcn_global_load_lds(
      (const __attribute__((address_space(1))) unsigned int*)g,
      (__attribute__((address_space(3))) unsigned int*)l, 16, 0, 0);
}

// ---- prep kernel: all independent prologue work in ONE dispatch -------------
struct PrepArgs {
  const float* W[4];
  unsigned short* Wt[4];
  int K[4];
  int N[4];
  const float* We;
  const float* be;
  const float* W1_0;
  unsigned short* WfT;
  const float* W2_2;
  const float* b2_2;
  const float* wtask;
  float* w2v;
  float* c2;
  float* nodedot;
  float* out;
  const float* b_task;
};

__global__ __launch_bounds__(256)
void prep_kernel(PrepArgs a) {
  const int blk = blockIdx.x;
  if (blk < 320) {
    int z, b;
    if (blk < 64)       { z = 0; b = blk; }
    else if (blk < 128) { z = 1; b = blk - 64; }
    else if (blk < 192) { z = 2; b = blk - 128; }
    else                { z = 3; b = blk - 192; }
    const int K = a.K[z], N = a.N[z];
    const int nt = N / 32;
    const int kb = (b / nt) * 32, nb = (b % nt) * 32;
    __shared__ unsigned short tile[32][33];
    const float* W = a.W[z];
    unsigned short* Wt = a.Wt[z];
    const int tx = threadIdx.x & 31, ty = threadIdx.x >> 5;
    for (int r = ty; r < 32; r += 8)
      tile[r][tx] = f2bf(W[(size_t)(kb + r) * N + nb + tx]);
    __syncthreads();
    for (int r = ty; r < 32; r += 8)
      Wt[(size_t)(nb + r) * K + kb + tx] = tile[tx][r];
  } else if (blk < 361) {
    const int k = blk - 320;  // 0..40
    const int n = threadIdx.x;
    if (k < 40) {
      float s = 0.f;
      for (int j = 0; j < 128; j++) s = fmaf(a.We[k * 128 + j], a.W1_0[(size_t)j * 256 + n], s);
      a.WfT[n * 64 + k] = f2bf(s);
    } else {
      float s = 0.f;
      for (int j = 0; j < 128; j++) s = fmaf(a.be[j], a.W1_0[(size_t)j * 256 + n], s);
      a.WfT[n * 64 + 40] = f2bf(s);
      for (int kk = 41; kk < 64; kk++) a.WfT[n * 64 + kk] = 0;
    }
  } else if (blk < 490) {
    const int p = blk - 361;  // 0..128
    const int lane = threadIdx.x & 63;
    const int wave = threadIdx.x >> 6;
    if (p < 128) {
      const int k = p * 4 + wave;
      const float* row = a.W2_2 + (size_t)k * 512 + lane * 8;
      float4 a0 = *(const float4*)(row);
      float4 a1 = *(const float4*)(row + 4);
      float4 w0 = *(const float4*)(a.wtask + lane * 8);
      float4 w1 = *(const float4*)(a.wtask + lane * 8 + 4);
      float s = a0.x * w0.x + a0.y * w0.y + a0.z * w0.z + a0.w * w0.w +
                a1.x * w1.x + a1.y * w1.y + a1.z * w1.z + a1.w * w1.w;
#pragma unroll
      for (int off = 32; off > 0; off >>= 1) s += __shfl_down(s, off);
      if (lane == 0) a.w2v[k] = s;
    } else if (wave == 0) {
      float4 a0 = *(const float4*)(a.b2_2 + lane * 8);
      float4 a1 = *(const float4*)(a.b2_2 + lane * 8 + 4);
      float4 w0 = *(const float4*)(a.wtask + lane * 8);
      float4 w1 = *(const float4*)(a.wtask + lane * 8 + 4);
      float s = a0.x * w0.x + a0.y * w0.y + a0.z * w0.z + a0.w * w0.w +
                a1.x * w1.x + a1.y * w1.y + a1.z * w1.z + a1.w * w1.w;
#pragma unroll
      for (int off = 32; off > 0; off >>= 1) s += __shfl_down(s, off);
      if (lane == 0) *a.c2 = s;
    }
  } else if (blk < 881) {
    int i = (blk - 490) * 256 + threadIdx.x;
    if (i < N_NODES) a.nodedot[i] = 0.f;
  } else {
    int g = (blk - 881) * 256 + threadIdx.x;
    if (g < N_GRAPHS) a.out[g] = a.b_task[0];
  }
}

// ---------------- CSR build: zero, histogram, scan, fill ---------------------
__global__ __launch_bounds__(256)
void zero_kernel(int* __restrict__ p, int n) {
  int i = blockIdx.x * 256 + threadIdx.x;
  if (i < n) p[i] = 0;
}

__global__ __launch_bounds__(256)
void hist_kernel(const int* __restrict__ ei, int* __restrict__ deg) {
  int e = blockIdx.x * 256 + threadIdx.x;
  if (e < E_EDGES) atomicAdd(&deg[ei[E_EDGES + e]], 1);
}

__global__ __launch_bounds__(256)
void scan_blk_kernel(const int* __restrict__ in, int* __restrict__ out,
                     int* __restrict__ blk_sums, int n_in, int n_out) {
  __shared__ int sm[256];
  const int t = threadIdx.x;
  const int base = blockIdx.x * 1024 + t * 4;
  int d0 = (base + 0 < n_in) ? in[base + 0] : 0;
  int d1 = (base + 1 < n_in) ? in[base + 1] : 0;
  int d2 = (base + 2 < n_in) ? in[base + 2] : 0;
  int d3 = (base + 3 < n_in) ? in[base + 3] : 0;
  int s = d0 + d1 + d2 + d3;
  sm[t] = s;
  __syncthreads();
  for (int off = 1; off < 256; off <<= 1) {
    int v = (t >= off) ? sm[t - off] : 0;
    __syncthreads();
    sm[t] += v;
    __syncthreads();
  }
  int excl = sm[t] - s;
  if (base + 0 < n_out) out[base + 0] = excl;
  if (base + 1 < n_out) out[base + 1] = excl + d0;
  if (base + 2 < n_out) out[base + 2] = excl + d0 + d1;
  if (base + 3 < n_out) out[base + 3] = excl + d0 + d1 + d2;
  if (t == 255 && blk_sums) blk_sums[blockIdx.x] = sm[255];
}

__global__ __launch_bounds__(256)
void scan_fix_kernel(int* __restrict__ row_ptr, const int* __restrict__ blk_off,
                     int* __restrict__ cursor) {
  int i = blockIdx.x * 256 + threadIdx.x;
  if (i <= N_NODES) {
    int v = row_ptr[i] + blk_off[i >> 10];
    row_ptr[i] = v;
    if (i < N_NODES) cursor[i] = v;
  }
}

__global__ __launch_bounds__(256)
void fill_kernel(const int* __restrict__ ei, int* __restrict__ cursor,
                 int* __restrict__ csr_src) {
  int e = blockIdx.x * 256 + threadIdx.x;
  if (e < E_EDGES) {
    int d = ei[E_EDGES + e];
    int slot = atomicAdd(&cursor[d], 1);
    csr_src[slot] = ei[e];
  }
}

// ---- gatherx: G[n,64] = bf16([(1+eps)X_n + sum X_src | f_n | 0...]) ---------
__global__ __launch_bounds__(256)
void gatherx_kernel(const float* __restrict__ X, unsigned short* __restrict__ G,
                    const int* __restrict__ row_ptr, const int* __restrict__ csr,
                    const float* __restrict__ eps) {
  const int node = blockIdx.x * 4 + (threadIdx.x >> 6);
  const int lane = threadIdx.x & 63;
  const float sc = 1.0f + eps[0];
  const int e0 = row_ptr[node];
  const int e1 = row_ptr[node + 1];
  float acc = 0.f;
  if (lane < 40) {
    acc = sc * X[(size_t)node * 40 + lane];
    int e = e0;
    for (; e + 4 <= e1; e += 4) {
      int s0 = csr[e], s1 = csr[e + 1], s2 = csr[e + 2], s3 = csr[e + 3];
      float a0 = X[(size_t)s0 * 40 + lane];
      float a1 = X[(size_t)s1 * 40 + lane];
      float a2 = X[(size_t)s2 * 40 + lane];
      float a3 = X[(size_t)s3 * 40 + lane];
      acc += (a0 + a1) + (a2 + a3);
    }
    for (; e < e1; e++)
      acc += X[(size_t)csr[e] * 40 + lane];
  } else if (lane == 40) {
    acc = sc + (float)(e1 - e0);
  }
  G[(size_t)node * 64 + lane] = f2bf(acc);
}

// ------- gather (D=256): Z[d] = bf16((1+eps)*H[d] + sum H[src]) --------------
// R14 exact form: ONE wave per node, uint2 (8B) loads, simple loop.
__global__ __launch_bounds__(256)
void gather_kernel(const unsigned short* __restrict__ H, unsigned short* __restrict__ Z,
                   const int* __restrict__ row_ptr, const int* __restrict__ csr,
                   const float* __restrict__ eps, int l) {
  const int node = blockIdx.x * 4 + (threadIdx.x >> 6);
  const int lane = threadIdx.x & 63;
  const float sc = 1.0f + eps[l];
  uint2 hv = *(const uint2*)(H + (size_t)node * 256 + lane * 4);
  float acc[4];
  acc[0] = sc * bf2f((unsigned short)(hv.x & 0xFFFF));
  acc[1] = sc * bf2f((unsigned short)(hv.x >> 16));
  acc[2] = sc * bf2f((unsigned short)(hv.y & 0xFFFF));
  acc[3] = sc * bf2f((unsigned short)(hv.y >> 16));
  const int e0 = row_ptr[node];
  const int e1 = row_ptr[node + 1];
  int e = e0;
  for (; e + 2 <= e1; e += 2) {
    int s0 = csr[e], s1 = csr[e + 1];
    uint2 a = *(const uint2*)(H + (size_t)s0 * 256 + lane * 4);
    uint2 b = *(const uint2*)(H + (size_t)s1 * 256 + lane * 4);
    acc[0] += bf2f((unsigned short)(a.x & 0xFFFF)) + bf2f((unsigned short)(b.x & 0xFFFF));
    acc[1] += bf2f((unsigned short)(a.x >> 16))    + bf2f((unsigned short)(b.x >> 16));
    acc[2] += bf2f((unsigned short)(a.y & 0xFFFF)) + bf2f((unsigned short)(b.y & 0xFFFF));
    acc[3] += bf2f((unsigned short)(a.y >> 16))    + bf2f((unsigned short)(b.y >> 16));
  }
  if (e < e1) {
    int s0 = csr[e];
    uint2 a = *(const uint2*)(H + (size_t)s0 * 256 + lane * 4);
    acc[0] += bf2f((unsigned short)(a.x & 0xFFFF));
    acc[1] += bf2f((unsigned short)(a.x >> 16));
    acc[2] += bf2f((unsigned short)(a.y & 0xFFFF));
    acc[3] += bf2f((unsigned short)(a.y >> 16));
  }
  unsigned short z[4] = {f2bf(acc[0]), f2bf(acc[1]), f2bf(acc[2]), f2bf(acc[3])};
  *(uint2*)(Z + (size_t)node * 256 + lane * 4) = *(uint2*)z;
}

// ============================================================================
// R21 (kept): fused per-layer MLP with minimum 2-phase pipeline (T3-min):
// per K-step {stage panel t+1 -> Bs[buf^1]; ds_read panel t; MFMA; ONE
// __syncthreads}. W-panel L2 latency hides under MFMA. 64 KB LDS -> 2
// blocks/CU. Swizzles as verified in R19.
// ============================================================================
template <int K1>
__global__ __launch_bounds__(256, 2)
void fused_mlp_kernel(const unsigned short* __restrict__ A,    // [M][K1]
                      const unsigned short* __restrict__ W1t,  // [256][K1]
                      const float* __restrict__ b1,            // [256]
                      const unsigned short* __restrict__ W2t,  // [256][256]
                      const float* __restrict__ b2,            // [256]
                      unsigned short* __restrict__ H,          // [M][256]
                      int M) {
  constexpr int ACH = K1 / 8;           // 16B chunks per A row (8 or 32)
  constexpr int ZP = (64 * ACH) / 256;  // cp16 issues/thread for Z (2 or 8)
  constexpr int NT1 = K1 / 32;          // phase-1 K-steps (2 or 8)

  __shared__ unsigned short Bs[2][256 * 32];  // 2 x 16 KB W-panel dbuf
  __shared__ unsigned short Ts[64 * 256];     // 32 KB (Z then T then H-stage)

  const int m0 = blockIdx.x * 64;
  const int tid = threadIdx.x;
  const int lane = tid & 63;
  const int wave = tid >> 6;
  const int fr = lane & 15;
  const int fq = lane >> 4;
  const int wn = wave * 64;

  // ---- stage Z once into Ts (per-lane pre-swizzled global source) ----
#pragma unroll
  for (int p = 0; p < ZP; p++) {
    int slot = p * 256 + tid;
    int row = slot / ACH;
    int cs = slot % ACH;
    int cg = cs ^ (row & 7);
    int grow = m0 + row;
    if (grow >= M) grow = M - 1;
    cp16(A + (size_t)grow * K1 + cg * 8, Ts + (size_t)(p * 256 + wn) * 8);
  }

  // ---- B staging source pointers (pre-swizzled, R19-verified) ----
  const int bn_ = tid >> 2;
  const int bc_ = tid & 3;
  const unsigned short* srcW1[4];
  const unsigned short* srcW2[4];
#pragma unroll
  for (int p = 0; p < 4; p++) {
    int n = p * 64 + bn_;
    int sw = (bc_ ^ ((n >> 1) & 3)) << 3;
    srcW1[p] = W1t + (size_t)n * K1 + sw;
    srcW2[p] = W2t + (size_t)n * 256 + sw;
  }

  // ---- B-frag LDS offsets (constant across K-steps) ----
  int offB[4];
#pragma unroll
  for (int j = 0; j < 4; j++) {
    int n = wn + j * 16 + fr;
    offB[j] = n * 32 + ((fq ^ ((n >> 1) & 3)) << 3);
  }

  // ---- stage W1 panel 0 into Bs[0] ----
#pragma unroll
  for (int p = 0; p < 4; p++)
    cp16(srcW1[p], &Bs[0][(size_t)(p * 256 + wn) * 8]);

  floatx4 acc[4][4];
#pragma unroll
  for (int i = 0; i < 4; i++)
#pragma unroll
    for (int j = 0; j < 4; j++) acc[i][j] = (floatx4){0.f, 0.f, 0.f, 0.f};

  __syncthreads();  // Z + W1 panel 0 staged & visible
  int buf = 0;

  // ---------------- phase 1: acc = Z @ W1t^T ----------------
  for (int t = 0; t < NT1; t++) {
    // prefetch next panel (last step prefetches W2 panel 0)
    if (t + 1 < NT1) {
#pragma unroll
      for (int p = 0; p < 4; p++)
        cp16(srcW1[p] + (t + 1) * 32, &Bs[buf ^ 1][(size_t)(p * 256 + wn) * 8]);
    } else {
#pragma unroll
      for (int p = 0; p < 4; p++)
        cp16(srcW2[p], &Bs[buf ^ 1][(size_t)(p * 256 + wn) * 8]);
    }
    shortx8 af[4], bv[4];
    const int kc = t * 4;
#pragma unroll
    for (int i = 0; i < 4; i++) {
      int row = i * 16 + fr;
      af[i] = *(const shortx8*)&Ts[row * K1 + (((kc + fq) ^ (fr & 7)) << 3)];
    }
#pragma unroll
    for (int j = 0; j < 4; j++) bv[j] = *(const shortx8*)&Bs[buf][offB[j]];
#pragma unroll
    for (int i = 0; i < 4; i++)
#pragma unroll
      for (int j = 0; j < 4; j++)
        acc[i][j] = __builtin_amdgcn_mfma_f32_16x16x32_bf16(af[i], bv[j], acc[i][j], 0, 0, 0);
    __syncthreads();  // drains prefetch (after compute) + orders buffer reuse
    buf ^= 1;
  }

  // ---- T = relu(acc + b1) overwrites Ts (all Ts reads done: loop-end sync) --
#pragma unroll
  for (int j = 0; j < 4; j++) {
    int col = wn + j * 16 + fr;
    float bb = b1[col];
    int cgc = col >> 3, c7 = col & 7;
#pragma unroll
    for (int i = 0; i < 4; i++)
#pragma unroll
      for (int r = 0; r < 4; r++) {
        int row = i * 16 + fq * 4 + r;
        float v = fmaxf(acc[i][j][r] + bb, 0.f);
        Ts[row * 256 + (((cgc ^ (row & 7)) << 3) | c7)] = f2bf(v);
        acc[i][j][r] = 0.f;
      }
  }
  __syncthreads();  // T visible; Bs[buf] holds W2 panel 0

  // ---------------- phase 2: acc = T @ W2t^T ----------------
  for (int t = 0; t < 8; t++) {
    if (t + 1 < 8) {
#pragma unroll
      for (int p = 0; p < 4; p++)
        cp16(srcW2[p] + (t + 1) * 32, &Bs[buf ^ 1][(size_t)(p * 256 + wn) * 8]);
    }
    shortx8 af[4], bv[4];
    const int kc = t * 4;
#pragma unroll
    for (int i = 0; i < 4; i++) {
      int row = i * 16 + fr;
      af[i] = *(const shortx8*)&Ts[row * 256 + (((kc + fq) ^ (fr & 7)) << 3)];
    }
#pragma unroll
    for (int j = 0; j < 4; j++) bv[j] = *(const shortx8*)&Bs[buf][offB[j]];
#pragma unroll
    for (int i = 0; i < 4; i++)
#pragma unroll
      for (int j = 0; j < 4; j++)
        acc[i][j] = __builtin_amdgcn_mfma_f32_16x16x32_bf16(af[i], bv[j], acc[i][j], 0, 0, 0);
    __syncthreads();
    buf ^= 1;
  }

  // ---- epilogue: H = relu(acc + b2), staged via Ts for coalesced stores ----
#pragma unroll
  for (int j = 0; j < 4; j++) {
    int col = wn + j * 16 + fr;
    float bb = b2[col];
    int cgc = col >> 3, c7 = col & 7;
#pragma unroll
    for (int i = 0; i < 4; i++)
#pragma unroll
      for (int r = 0; r < 4; r++) {
        int row = i * 16 + fq * 4 + r;
        float v = fmaxf(acc[i][j][r] + bb, 0.f);
        Ts[row * 256 + (((cgc ^ (row & 7)) << 3) | c7)] = f2bf(v);
      }
  }
  __syncthreads();
  const int r2 = tid >> 5;    // 0..7
  const int cg2 = tid & 31;   // output 16B chunk
#pragma unroll
  for (int p = 0; p < 8; p++) {
    int row = p * 8 + r2;
    int grow = m0 + row;
    if (grow < M) {
      uint4 v = *(const uint4*)&Ts[row * 256 + ((cg2 ^ (row & 7)) << 3)];
      *(uint4*)&H[(size_t)grow * 256 + cg2 * 8] = v;
    }
  }
}

// ============================================================================
// R21 (kept): fused layer-2 + task-dot, 2-phase pipeline, 16 flattened
// K-steps; per-wave partials -> nodedot4[wave][row] via PLAIN stores.
// ============================================================================
__global__ __launch_bounds__(256, 2)
void fused_dot_kernel(const unsigned short* __restrict__ A,    // Z [M][256]
                      const unsigned short* __restrict__ W1t,  // [512][256]
                      const float* __restrict__ b1,            // [512]
                      const float* __restrict__ w2v,           // [512]
                      float* __restrict__ nodedot4, int M) {
  __shared__ unsigned short Bs[2][256 * 32];  // 2 x 16 KB
  __shared__ unsigned short Ts[64 * 256];     // 32 KB (Z)

  const int m0 = blockIdx.x * 64;
  const int tid = threadIdx.x;
  const int lane = tid & 63;
  const int wave = tid >> 6;
  const int fr = lane & 15;
  const int fq = lane >> 4;
  const int wn = wave * 64;

#pragma unroll
  for (int p = 0; p < 8; p++) {
    int slot = p * 256 + tid;
    int row = slot >> 5;
    int cs = slot & 31;
    int cg = cs ^ (row & 7);
    int grow = m0 + row;
    if (grow >= M) grow = M - 1;
    cp16(A + (size_t)grow * 256 + cg * 8, Ts + (size_t)(p * 256 + wn) * 8);
  }

  const int bn_ = tid >> 2;
  const int bc_ = tid & 3;
  const unsigned short* srcW[4];
#pragma unroll
  for (int p = 0; p < 4; p++) {
    int n = p * 64 + bn_;
    srcW[p] = W1t + (size_t)n * 256 + ((bc_ ^ ((n >> 1) & 3)) << 3);
  }
  int offB[4];
#pragma unroll
  for (int j = 0; j < 4; j++) {
    int n = wn + j * 16 + fr;
    offB[j] = n * 32 + ((fq ^ ((n >> 1) & 3)) << 3);
  }

  // stage W panel for step 0 (nh=0, k0=0)
#pragma unroll
  for (int p = 0; p < 4; p++)
    cp16(srcW[p], &Bs[0][(size_t)(p * 256 + wn) * 8]);

  float pd[4][4];
#pragma unroll
  for (int i = 0; i < 4; i++)
#pragma unroll
    for (int r = 0; r < 4; r++) pd[i][r] = 0.f;

  floatx4 acc[4][4];
#pragma unroll
  for (int i = 0; i < 4; i++)
#pragma unroll
    for (int j = 0; j < 4; j++) acc[i][j] = (floatx4){0.f, 0.f, 0.f, 0.f};

  __syncthreads();  // Z + panel 0 staged
  int buf = 0;

  // 16 flattened K-steps: s = nh*8 + t; panel offset = nh*65536 + t*32
  for (int s = 0; s < 16; s++) {
    int ns = s + 1;
    if (ns < 16) {
      const size_t off = (size_t)(ns >> 3) * 65536 + (size_t)(ns & 7) * 32;
#pragma unroll
      for (int p = 0; p < 4; p++)
        cp16(srcW[p] + off, &Bs[buf ^ 1][(size_t)(p * 256 + wn) * 8]);
    }
    shortx8 af[4], bv[4];
    const int kc = (s & 7) * 4;
#pragma unroll
    for (int i = 0; i < 4; i++) {
      int row = i * 16 + fr;
      af[i] = *(const shortx8*)&Ts[row * 256 + (((kc + fq) ^ (fr & 7)) << 3)];
    }
#pragma unroll
    for (int j = 0; j < 4; j++) bv[j] = *(const shortx8*)&Bs[buf][offB[j]];
#pragma unroll
    for (int i = 0; i < 4; i++)
#pragma unroll
      for (int j = 0; j < 4; j++)
        acc[i][j] = __builtin_amdgcn_mfma_f32_16x16x32_bf16(af[i], bv[j], acc[i][j], 0, 0, 0);
    __syncthreads();
    buf ^= 1;

    if ((s & 7) == 7) {  // end of a 256-col half: fold into pd, reset acc
      const int nh = s >> 3;
#pragma unroll
      for (int j = 0; j < 4; j++) {
        int col = nh * 256 + wn + j * 16 + fr;
        float bb = b1[col];
        float wv = w2v[col];
#pragma unroll
        for (int i = 0; i < 4; i++)
#pragma unroll
          for (int r = 0; r < 4; r++) {
            pd[i][r] += fmaxf(acc[i][j][r] + bb, 0.f) * wv;
            acc[i][j][r] = 0.f;
          }
      }
    }
  }

#pragma unroll
  for (int i = 0; i < 4; i++)
#pragma unroll
    for (int r = 0; r < 4; r++) {
      float s = pd[i][r];
#pragma unroll
      for (int off = 1; off < 16; off <<= 1) s += __shfl_xor(s, off);
      if (fr == 0) {
        int row = m0 + i * 16 + fq * 4 + r;
        // plain store: plane `wave`, row owned by exactly this block
        if (row < M) nodedot4[(size_t)wave * N_NODES + row] = s;
      }
    }
}

// ---------------- readout ----------------------------------------------------
// R22: parallel pool. R21's pool was 73.6us at 0.23% occupancy (7 blocks,
// serial 64-node walk/thread -- latency-bound by the roofline table's "both
// low, grid tiny" row). Now: one THREAD per node; wave-level key-segmented
// inclusive scan (batch sorted) -> one atomicAdd per graph-run per wave
// (~5.6K atomics total). Tail-safe: shfl_up reads only lower (active) lanes;
// run-end test uses batch[i+1] load, not shfl_down.
__global__ __launch_bounds__(256)
void pool_kernel(const float* __restrict__ nodedot4, const int* __restrict__ batch,
                 float* __restrict__ out, const float* __restrict__ c2p) {
  const int i = blockIdx.x * 256 + threadIdx.x;
  if (i >= N_NODES) return;
  const int lane = threadIdx.x & 63;
  const float c2 = *c2p;
  float v = (nodedot4[i] + nodedot4[N_NODES + i]) +
            (nodedot4[2 * N_NODES + i] + nodedot4[3 * N_NODES + i]) + c2;
  const int g = batch[i];
  float s = v;
#pragma unroll
  for (int off = 1; off < 64; off <<= 1) {
    float u = __shfl_up(s, off);
    int gu = __shfl_up(g, off);
    if (lane >= off && gu == g) s += u;
  }
  bool last = (i == N_NODES - 1) || (batch[i + 1] != g) || (lane == 63);
  if (last) unsafeAtomicAdd(&out[g], s);
}

extern "C" void kernel_launch(void* const* d_in, const int* in_sizes, int n_in,
                              void* d_out, int out_size, void* d_ws, size_t ws_size,
                              hipStream_t stream) {
  const float* x       = (const float*)d_in[0];
  const int*   ei      = (const int*)d_in[1];
  const int*   batch   = (const int*)d_in[2];
  const float* W_embed = (const float*)d_in[3];
  const float* b_embed = (const float*)d_in[4];
  const float* eps     = (const float*)d_in[5];
  const float* W1[3] = {(const float*)d_in[6],  (const float*)d_in[10], (const float*)d_in[14]};
  const float* B1[3] = {(const float*)d_in[7],  (const float*)d_in[11], (const float*)d_in[15]};
  const float* W2[3] = {(const float*)d_in[8],  (const float*)d_in[12], (const float*)d_in[16]};
  const float* B2[3] = {(const float*)d_in[9],  (const float*)d_in[13], (const float*)d_in[17]};
  const float* W_task = (const float*)d_in[18];
  const float* b_task = (const float*)d_in[19];
  float* out = (float*)d_out;

  const size_t OFF_ND4 = 51200000;   // old RB region, free since R18: 4x100000 floats
  const size_t OFF_RZ  = 102400000;
  const size_t OFF_AUX = 153600000;
  if (ws_size < OFF_AUX + 4000000) return;
  unsigned short* RH = (unsigned short*)d_ws;
  float* nodedot4 = (float*)((char*)d_ws + OFF_ND4);
  unsigned short* RZ = (unsigned short*)((char*)d_ws + OFF_RZ);
  char* aux = (char*)d_ws + OFF_AUX;
  int* row_ptr  = (int*)(aux);               // 100001 ints
  int* cursor   = (int*)(aux + 400016);      // 100000 ints (also deg histogram)
  int* csr_src  = (int*)(aux + 800016);      // 300000 ints
  int* blk_sums = (int*)(aux + 2000016);     // 98 ints
  int* blk_off  = (int*)(aux + 2000416);     // 98 ints
  float* nodedot = (float*)(aux + 2000816);  // 100000 floats (legacy zero, unused)
  unsigned short* WT = (unsigned short*)(aux + 2400832);  // 360448 bf16
  float* w2v = (float*)(aux + 3200832);      // 512 floats
  float* c2  = (float*)(aux + 3202880);      // 1 float
  unsigned short* WfT    = WT;
  unsigned short* Wt2_0  = WT + 32768;
  unsigned short* Wt1_1  = WT + 98304;
  unsigned short* Wt2_1  = WT + 163840;
  unsigned short* Wt1_2  = WT + 229376;

  // ---- prep: all independent prologue work (1 dispatch) ----
  PrepArgs pa;
  pa.W[0] = W2[0]; pa.Wt[0] = Wt2_0; pa.K[0] = 256; pa.N[0] = 256;
  pa.W[1] = W1[1]; pa.Wt[1] = Wt1_1; pa.K[1] = 256; pa.N[1] = 256;
  pa.W[2] = W2[1]; pa.Wt[2] = Wt2_1; pa.K[2] = 256; pa.N[2] = 256;
  pa.W[3] = W1[2]; pa.Wt[3] = Wt1_2; pa.K[3] = 256; pa.N[3] = 512;
  pa.We = W_embed; pa.be = b_embed; pa.W1_0 = W1[0]; pa.WfT = WfT;
  pa.W2_2 = W2[2]; pa.b2_2 = B2[2]; pa.wtask = W_task; pa.w2v = w2v; pa.c2 = c2;
  pa.nodedot = nodedot; pa.out = out; pa.b_task = b_task;
  prep_kernel<<<889, 256, 0, stream>>>(pa);

  // ---- CSR build ----
  zero_kernel<<<(N_NODES + 255) / 256, 256, 0, stream>>>(cursor, N_NODES);
  hist_kernel<<<(E_EDGES + 255) / 256, 256, 0, stream>>>(ei, cursor);
  scan_blk_kernel<<<98, 256, 0, stream>>>(cursor, row_ptr, blk_sums, N_NODES, N_NODES + 1);
  scan_blk_kernel<<<1, 256, 0, stream>>>(blk_sums, blk_off, nullptr, 98, 98);
  scan_fix_kernel<<<(N_NODES + 256) / 256, 256, 0, stream>>>(row_ptr, blk_off, cursor);
  fill_kernel<<<(E_EDGES + 255) / 256, 256, 0, stream>>>(ei, cursor, csr_src);

  const int FB = (N_NODES + 63) / 64;  // 1563 fused blocks (64 rows each)

  // ---- layer 0 (folded embed): G -> H = relu(relu(G@WfT^T+b1)@W2_0+b2) ----
  gatherx_kernel<<<N_NODES / 4, 256, 0, stream>>>(x, RZ, row_ptr, csr_src, eps);
  fused_mlp_kernel<64><<<FB, 256, 0, stream>>>(RZ, WfT, B1[0], Wt2_0, B2[0], RH, N_NODES);

  // ---- layer 1 ----
  gather_kernel<<<N_NODES / 4, 256, 0, stream>>>(RH, RZ, row_ptr, csr_src, eps, 1);
  fused_mlp_kernel<256><<<FB, 256, 0, stream>>>(RZ, Wt1_1, B1[1], Wt2_1, B2[1], RH, N_NODES);

  // ---- layer 2: gather, then fused GEMM + task-dot ----
  gather_kernel<<<N_NODES / 4, 256, 0, stream>>>(RH, RZ, row_ptr, csr_src, eps, 2);
  fused_dot_kernel<<<FB, 256, 0, stream>>>(RZ, Wt1_2, B1[2], w2v, nodedot4, N_NODES);

  // ---- out[g] = b_task + sum_i (sum_w nodedot4[w][i] + c2) ----
  pool_kernel<<<(N_NODES + 255) / 256, 256, 0, stream>>>(nodedot4, batch, out, c2);
}